// Round 12
// baseline (1000.036 us; speedup 1.0000x reference)
//
#include <hip/hip_runtime.h>
#include <cstdint>
#include <cstddef>

#define HW    1444      // 38*38
#define NA    12996     // HW*9
#define NPRE  3000
#define NW    47        // ceil(3000/64)
#define NPOST 300

// d_out section offsets (in floats)
#define OFF_LOCS   0         // 4*12996*4 = 207936
#define OFF_SCORES 207936    // 4*12996*2 = 103968
#define OFF_ROIS   311904    // 1200*4    = 4800
#define OFF_IDX    316704    // 4*300     = 1200
#define OFF_ANCH   317904    // 12996*4   = 51984

#define INVALID_KEY 0xFFF0000000000000ULL

typedef float f32x2 __attribute__((ext_vector_type(2)));
typedef float f32x4 __attribute__((ext_vector_type(4)));

__device__ inline double as_dim(int raw) {
  if (raw > 0 && raw < 1000000) return (double)raw;
  return (double)__int_as_float(raw);
}

// -------- W transpose + keys padding (idle-thread fusion) -------------------
__global__ __launch_bounds__(256) void wt_k(const float* __restrict__ lw,
                                            const float* __restrict__ sw,
                                            float* __restrict__ Wt,
                                            unsigned long long* __restrict__ keys) {
  int t = blockIdx.x * 256 + threadIdx.x;
  if (t < 4 * (16384 - NA)) {            // 13552 pad keys
    int n2 = t / (16384 - NA), r = t - n2 * (16384 - NA);
    keys[((size_t)n2 << 14) + NA + r] = ~0ULL;
  }
  if (t >= 64 * 512) return;
  int o = t & 63, c = t >> 6;
  float v = 0.f;
  if (o < 36)      v = lw[o * 512 + c];
  else if (o < 54) v = sw[(o - 36) * 512 + c];
  Wt[t] = v;
}

// ------- 3x3 conv: R9 VERBATIM (best measured: 564-573us, 0 conflicts) -----
__global__ __launch_bounds__(256) void conv_k(const float* __restrict__ X,
                                              const float* __restrict__ W,
                                              const float* __restrict__ B,
                                              float* __restrict__ F) {
  __shared__ float Xs[1008];   // A: [4cl][3row][40]=480 | B: [4cl][3row][44]=528
  __shared__ float Wsf[2304];  // [o=64][36] f32, 9216 B, lane-contiguous
  const int tid  = threadIdx.x;
  const int lane = tid & 63;
  const int wv   = tid >> 6;
  const int seg  = wv * 10;
  const int y  = blockIdx.x;
  const int o0 = blockIdx.y * 64;
  const int n  = blockIdx.z;
  const float* xn = X + ((size_t)n * 512) * HW;

  int xsrcA[2]; bool xvalA[2]; bool xactA1;
  {
    int e = tid;
    int cl = e / 120, rem = e - cl * 120, row = rem / 40, colA = rem - row * 40;
    int m = colA - 1, iy = y - 1 + row;
    xvalA[0] = (m >= 0 && m < 38 && iy >= 0 && iy < 38);
    xsrcA[0] = xvalA[0] ? (cl * HW + iy * 38 + m) : 0;
  }
  {
    int e = tid + 256; xactA1 = (e < 480);
    int cl = e / 120, rem = e - cl * 120, row = rem / 40, colA = rem - row * 40;
    int m = colA - 1, iy = y - 1 + row;
    xvalA[1] = xactA1 && (m >= 0 && m < 38 && iy >= 0 && iy < 38);
    xsrcA[1] = xvalA[1] ? (cl * HW + iy * 38 + m) : 0;
  }
  int xsrcB[3]; bool xvalB[3]; bool xactB2;
#pragma unroll
  for (int u = 0; u < 3; ++u) {
    int e = tid + u * 256;
    bool act = (e < 528);
    int cl = e / 132, rem = e - cl * 132, row = rem / 44, colB = rem - row * 44;
    int m = colB - 3, iy = y - 1 + row;
    xvalB[u] = act && (m >= 0 && m < 38 && iy >= 0 && iy < 38);
    xsrcB[u] = xvalB[u] ? (cl * HW + iy * 38 + m) : 0;
    if (u == 2) xactB2 = act;
  }
  int wsrc[9];
#pragma unroll
  for (int u = 0; u < 9; ++u) {
    int e = tid + u * 256;
    int ol = e / 36, t36 = e - ol * 36;
    wsrc[u] = (o0 + ol) * 4608 + t36;
  }

  float xrA[2], xrB[3], wr_[9];
#pragma unroll
  for (int u = 0; u < 2; ++u) xrA[u] = xvalA[u] ? xn[xsrcA[u]] : 0.f;
#pragma unroll
  for (int u = 0; u < 3; ++u) xrB[u] = xvalB[u] ? xn[xsrcB[u]] : 0.f;
#pragma unroll
  for (int u = 0; u < 9; ++u) wr_[u] = W[wsrc[u]];

  double acc[10];
#pragma unroll
  for (int p = 0; p < 10; ++p) acc[p] = 0.;
  f32x2 pA[5], pB[5];
  float pc0 = 0.f;

  const int  xb0   = (wv & 1) ? (480 + seg + 2) : seg;
  const int  cstep = (wv & 1) ? 132 : 120;
  const int  kstep = (wv & 1) ? 44 : 40;

#define WQ_ELEM(t) ((t & 3) == 0 ? wq[(t) >> 2].x : (t & 3) == 1 ? wq[(t) >> 2].y : \
                    (t & 3) == 2 ? wq[(t) >> 2].z : wq[(t) >> 2].w)

  for (int cc = 0; cc < 128; ++cc) {
    __syncthreads();
    Xs[tid] = xrA[0];
    if (xactA1) Xs[tid + 256] = xrA[1];
    Xs[480 + tid] = xrB[0];
    Xs[480 + tid + 256] = xrB[1];
    if (xactB2) Xs[480 + tid + 512] = xrB[2];
#pragma unroll
    for (int u = 0; u < 9; ++u) Wsf[tid + u * 256] = wr_[u];
    __syncthreads();
    if (cc < 127) {
      const int cb = (cc + 1) * 4;
#pragma unroll
      for (int u = 0; u < 2; ++u) xrA[u] = xvalA[u] ? xn[cb * HW + xsrcA[u]] : 0.f;
#pragma unroll
      for (int u = 0; u < 3; ++u) xrB[u] = xvalB[u] ? xn[cb * HW + xsrcB[u]] : 0.f;
#pragma unroll
      for (int u = 0; u < 9; ++u) wr_[u] = W[wsrc[u] + (cc + 1) * 36];
    }
    f32x4 wq[9];
    {
      const f32x4* wrow = (const f32x4*)&Wsf[lane * 36];
#pragma unroll
      for (int q = 0; q < 9; ++q) wq[q] = wrow[q];
    }
    if ((cc & 1) == 0) {
#pragma unroll
      for (int a = 0; a < 5; ++a) { pA[a] = (f32x2)(0.f); pB[a] = (f32x2)(0.f); }
      pc0 = 0.f;
    }
#pragma unroll
    for (int cl = 0; cl < 4; ++cl) {
      f32x2 wp[9];
#pragma unroll
      for (int k = 0; k < 9; ++k) {
        float wv0 = WQ_ELEM(cl * 9 + k);
        wp[k][0] = wv0; wp[k][1] = wv0;
      }
#pragma unroll
      for (int ky = 0; ky < 3; ++ky) {
        const float* xrow = &Xs[xb0 + cl * cstep + ky * kstep]; // 16B-aligned
        f32x4 q0 = *(const f32x4*)(xrow);
        f32x4 q1 = *(const f32x4*)(xrow + 4);
        f32x4 q2 = *(const f32x4*)(xrow + 8);
        f32x2 xp[6];
        xp[0] = __builtin_shufflevector(q0, q0, 0, 1);
        xp[1] = __builtin_shufflevector(q0, q0, 2, 3);
        xp[2] = __builtin_shufflevector(q1, q1, 0, 1);
        xp[3] = __builtin_shufflevector(q1, q1, 2, 3);
        xp[4] = __builtin_shufflevector(q2, q2, 0, 1);
        xp[5] = __builtin_shufflevector(q2, q2, 2, 3);
#pragma unroll
        for (int a = 0; a < 5; ++a)
          asm("v_pk_fma_f32 %0, %1, %2, %0"
              : "+v"(pA[a]) : "v"(xp[a]), "v"(wp[ky * 3 + 0]));
        pc0 = fmaf(wp[ky * 3 + 1][0], xp[0][1], pc0);
#pragma unroll
        for (int a = 0; a < 5; ++a)
          asm("v_pk_fma_f32 %0, %1, %2, %0"
              : "+v"(pB[a]) : "v"(xp[a + 1]), "v"(wp[ky * 3 + 1]));
#pragma unroll
        for (int a = 0; a < 5; ++a)
          asm("v_pk_fma_f32 %0, %1, %2, %0"
              : "+v"(pA[a]) : "v"(xp[a + 1]), "v"(wp[ky * 3 + 2]));
      }
    }
    if (cc & 1) {
      acc[0] += (double)(pA[0][0] + pc0);
#pragma unroll
      for (int p = 1; p < 10; ++p) {
        float sa = pA[p >> 1][p & 1];
        float sb = (p & 1) ? pB[(p - 1) >> 1][0] : pB[(p - 2) >> 1][1];
        acc[p] += (double)(sa + sb);
      }
    }
  }
  double bb = (double)B[o0 + lane];
  float* fp = F + ((size_t)(n * 512 + o0 + lane)) * HW + y * 38;
#pragma unroll
  for (int p = 0; p < 10; ++p) {
    int col = seg + p;
    if (col < 38) fp[col] = (float)fmax(acc[p] + bb, 0.0);
  }
}

// ------- 1x1 heads + softmax + FUSED decode/keys (R11 verbatim) -------------
__global__ __launch_bounds__(256) void heads_k(const float* __restrict__ F,
                                               const float* __restrict__ Wt,
                                               const float* __restrict__ lb,
                                               const float* __restrict__ sb,
                                               const int* __restrict__ ihp,
                                               const int* __restrict__ iwp,
                                               float* __restrict__ out,
                                               double* __restrict__ boxes,
                                               unsigned long long* __restrict__ keys) {
  __shared__ float sf[512 * 4];
  __shared__ double ssc[4][18];
  __shared__ float sloc[4][36];
  int n = blockIdx.y;
  int p0 = blockIdx.x * 4;
  int tid = threadIdx.x;
  const float* fn = F + ((size_t)n * 512) * HW;
  for (int e = tid; e < 2048; e += 256) {
    int c = e >> 2, pl = e & 3;
    sf[e] = fn[c * HW + p0 + pl];
  }
  __syncthreads();
  int pl = tid & 3, o = tid >> 2;
  double acc = 0.;
  if (o < 54) {
    for (int c = 0; c < 512; ++c)
      acc = fma((double)Wt[(c << 6) | o], (double)sf[(c << 2) | pl], acc);
  }
  int p = p0 + pl;
  if (o < 36) {
    acc += (double)lb[o];
    float v = (float)acc;
    out[OFF_LOCS + ((size_t)n * NA + (size_t)p * 9 + (o >> 2)) * 4 + (o & 3)] = v;
    sloc[pl][o] = v;
  } else if (o < 54) {
    int oo = o - 36;
    acc += (double)sb[oo];
    out[OFF_SCORES + ((size_t)n * NA + (size_t)p * 9 + (oo >> 1)) * 2 + (oo & 1)] = (float)acc;
    ssc[pl][oo] = acc;
  }
  __syncthreads();
  if (tid < 36) {
    int pl2 = tid / 9, a = tid - pl2 * 9;
    double s0 = ssc[pl2][a * 2], s1 = ssc[pl2][a * 2 + 1];
    double mx = fmax(s0, s1);
    double e0 = exp(s0 - mx), e1 = exp(s1 - mx);
    double sc = e1 / (e0 + e1);
    int pp = p0 + pl2;
    int i = pp * 9 + a;
    int ri = a / 3, si = a - ri * 3;
    double sr  = (ri == 0) ? 0.7071067811865476 : (ri == 1 ? 1.0 : 1.4142135623730951);
    double sri = (ri == 0) ? 1.4142135623730951 : (ri == 1 ? 1.0 : 0.7071067811865476);
    double hs = (double)(128 << si) * sr;
    double wd = (double)(128 << si) * sri;
    int py = pp / 38, px = pp - py * 38;
    float sx = (float)(px * 16), sy = (float)(py * 16);
    float fx1 = (float)(8.0 - 0.5 * wd), fy1 = (float)(8.0 - 0.5 * hs);
    float fx2 = (float)(8.0 + 0.5 * wd), fy2 = (float)(8.0 + 0.5 * hs);
    float ax1f = sx + fx1, ay1f = sy + fy1, ax2f = sx + fx2, ay2f = sy + fy2;
    if (n == 0) {
      float* ap = out + OFF_ANCH + (size_t)i * 4;
      ap[0] = ax1f; ap[1] = ay1f; ap[2] = ax2f; ap[3] = ay2f;
    }
    double ax1 = ax1f, ay1 = ay1f, ax2 = ax2f, ay2 = ay2f;
    double aw = ax2 - ax1, ah = ay2 - ay1;
    double acx = ax1 + 0.5 * aw, acy = ay1 + 0.5 * ah;
    double l0 = (double)sloc[pl2][a * 4 + 0], l1 = (double)sloc[pl2][a * 4 + 1];
    double l2 = (double)sloc[pl2][a * 4 + 2], l3 = (double)sloc[pl2][a * 4 + 3];
    double cx = l0 * aw + acx, cy = l1 * ah + acy;
    double bw = aw * exp(l2), bh = ah * exp(l3);
    double iwf = as_dim(iwp[0]), ihf = as_dim(ihp[0]);
    double x1 = fmin(fmax(cx - 0.5 * bw, 0.0), iwf);
    double y1 = fmin(fmax(cy - 0.5 * bh, 0.0), ihf);
    double x2 = fmin(fmax(cx + 0.5 * bw, 0.0), iwf);
    double y2 = fmin(fmax(cy + 0.5 * bh, 0.0), ihf);
    bool valid = ((x2 - x1) >= 16.0) && ((y2 - y1) >= 16.0);
    double* bp = boxes + ((size_t)n * NA + i) * 4;
    bp[0] = x1; bp[1] = y1; bp[2] = x2; bp[3] = y2;
    unsigned long long u = (unsigned long long)__double_as_longlong(sc);
    u = (u >> 63) ? ~u : (u | 0x8000000000000000ULL);
    unsigned long long inv = ~u;
    if (!valid) inv = INVALID_KEY;
    keys[((size_t)n << 14) + i] = (inv & ~0x3FFFULL) | (unsigned long long)i;
  }
}

// ---- sort A1: bitonic sizes 2..2048 within 2048-elem chunks (32 blocks) ----
// Exact restriction of the original 8192 network to sizes<=2048 (all pairs
// stay inside aligned 2048-chunks); direction recomputed from GLOBAL index:
// up = ((gidx & size)==0) ^ (gidx>=8192)  — bit-identical key stream.
__global__ __launch_bounds__(1024) void sortA1_k(unsigned long long* __restrict__ keys) {
  __shared__ unsigned long long s[2048];
  const int c = blockIdx.x;          // 0..31 = 4 batches x 8 chunks
  const int batch = c >> 3, chunk = c & 7;
  unsigned long long* g = keys + ((size_t)batch << 14) + ((size_t)chunk << 11);
  const int tid = threadIdx.x;       // 1024
  for (int i = tid; i < 2048; i += 1024) s[i] = g[i];
  const int gbase = chunk << 11;
  const bool hflip = (chunk >= 4);   // global element >= 8192
  for (int size = 2; size <= 2048; size <<= 1) {
    for (int stride = size >> 1; stride > 0; stride >>= 1) {
      __syncthreads();
      int u = tid;
      int lo = u & (stride - 1);
      int i1 = ((u - lo) << 1) | lo;
      int i2 = i1 + stride;
      bool up = (((gbase + i1) & size) == 0);
      if (hflip) up = !up;
      unsigned long long a = s[i1], b = s[i2];
      if ((a > b) == up) { s[i1] = b; s[i2] = a; }
    }
  }
  __syncthreads();
  for (int i = tid; i < 2048; i += 1024) g[i] = s[i];
}

// ---- sort A2: bitonic sizes 4096+8192 per half (8 blocks) ------------------
// The original sortA loop restricted to sizes {4096, 8192} — together with
// A1 this is exactly the original network (half0 asc, half1 desc).
__global__ __launch_bounds__(1024) void sortA2_k(unsigned long long* __restrict__ keys) {
  __shared__ unsigned long long s[8192];
  const int half = blockIdx.x & 1;
  unsigned long long* g = keys + (((size_t)(blockIdx.x >> 1)) << 14) + ((size_t)half << 13);
  const int tid = threadIdx.x;
  for (int i = tid; i < 8192; i += 1024) s[i] = g[i];
  for (int size = 4096; size <= 8192; size <<= 1) {
    for (int stride = size >> 1; stride > 0; stride >>= 1) {
      __syncthreads();
      for (int u = tid; u < 4096; u += 1024) {
        int lo = u & (stride - 1);
        int i1 = ((u - lo) << 1) | lo;
        int i2 = i1 + stride;
        bool up = (i1 & size) == 0;
        if (half) up = !up;
        unsigned long long a = s[i1], b = s[i2];
        if ((a > b) == up) { s[i1] = b; s[i2] = a; }
      }
    }
  }
  __syncthreads();
  for (int i = tid; i < 8192; i += 1024) g[i] = s[i];
}

// ---- sort final merge + gather, FUSED (R11 verbatim) -----------------------
__global__ __launch_bounds__(1024) void sortCG_k(const unsigned long long* __restrict__ keys,
                                                 const double* __restrict__ boxes,
                                                 double* __restrict__ bsort,
                                                 unsigned long long* __restrict__ vw) {
  __shared__ unsigned long long s[8192];
  const int n = blockIdx.x;
  const unsigned long long* g = keys + ((size_t)n << 14);
  const int tid = threadIdx.x;
  for (int i = tid; i < 8192; i += 1024) {
    unsigned long long a = g[i], b = g[i + 8192];
    s[i] = a < b ? a : b;
  }
  for (int stride = 4096; stride > 0; stride >>= 1) {
    __syncthreads();
    for (int u = tid; u < 4096; u += 1024) {
      int lo = u & (stride - 1);
      int i1 = ((u - lo) << 1) | lo;
      int i2 = i1 + stride;
      unsigned long long a = s[i1], b = s[i2];
      if (a > b) { s[i1] = b; s[i2] = a; }
    }
  }
  __syncthreads();
  const int lane = tid & 63;
#pragma unroll
  for (int r3 = 0; r3 < 3; ++r3) {
    int r = r3 * 1024 + tid;
    bool valid = false;
    if (r < NPRE) {
      unsigned long long kk = s[r];
      valid = kk < INVALID_KEY;
      unsigned idx = (unsigned)(kk & 0x3FFFULL);
      const double* bp = boxes + ((size_t)n * NA + idx) * 4;
      double* dp = bsort + ((size_t)n * NPRE + r) * 4;
      dp[0] = bp[0]; dp[1] = bp[1]; dp[2] = bp[2]; dp[3] = bp[3];
    }
    unsigned long long mask = __ballot(valid);
    int w = r >> 6;
    if (lane == 0 && w < NW) vw[n * NW + w] = mask;
  }
}

// ------- suppression matrix, TRANSPOSED access (R12) ------------------------
// Old layout: consecutive lanes = consecutive w (same i) -> inner-loop bj
// loads touched 64 cache lines per wave-load (~18 MB L2 traffic per CU).
// New: lane = i (bi coalesced), j wave-uniform (bj broadcast, 1 line).
// Words staged in LDS tile, written out coalesced. Predicate arithmetic
// IDENTICAL (mul-form threshold, same operands) -> sup bit-identical.
__global__ __launch_bounds__(256) void iou_k(const double* __restrict__ bsort,
                                             unsigned long long* __restrict__ sup) {
  __shared__ unsigned long long tile[64 * 49];   // stride 49: 2-way free banks
  const int ib = blockIdx.x;        // i-block 0..46
  const int n  = blockIdx.y;
  const int tid = threadIdx.x;
  const int lane = tid & 63;
  const int wv = tid >> 6;          // 0..3
  const int i0 = ib * 64;
  const int i  = i0 + lane;
  const int iclamp = i < NPRE ? i : NPRE - 1;
  const double* bb = bsort + (size_t)n * NPRE * 4;
  double bix1 = bb[(size_t)iclamp * 4 + 0], biy1 = bb[(size_t)iclamp * 4 + 1];
  double bix2 = bb[(size_t)iclamp * 4 + 2], biy2 = bb[(size_t)iclamp * 4 + 3];
  double ai = (bix2 - bix1) * (biy2 - biy1);
  for (int w = wv; w < NW; w += 4) {
    int j0 = w << 6;
    unsigned long long word = 0ULL;
    if (j0 + 63 > i0) {
      int lmax = NPRE - j0; if (lmax > 64) lmax = 64;
      for (int l2 = 0; l2 < lmax; ++l2) {
        int j = j0 + l2;
        const double* bj = bb + (size_t)j * 4;   // wave-uniform address
        double bjx1 = bj[0], bjy1 = bj[1], bjx2 = bj[2], bjy2 = bj[3];
        double aj = (bjx2 - bjx1) * (bjy2 - bjy1);
        double xx1 = fmax(bix1, bjx1), yy1 = fmax(biy1, bjy1);
        double xx2 = fmin(bix2, bjx2), yy2 = fmin(biy2, bjy2);
        double inter = fmax(xx2 - xx1, 0.0) * fmax(yy2 - yy1, 0.0);
        double uni = ai + aj - inter;
        bool supb = (j > i) && (uni > 0.0) && (inter > 0.7 * uni);
        word |= (unsigned long long)supb << l2;
      }
    }
    tile[lane * 49 + w] = word;
  }
  __syncthreads();
  int rows = NPRE - i0; if (rows > 64) rows = 64;
  int total = rows * NW;
  unsigned long long* gout = sup + ((size_t)n * NPRE + i0) * NW;
  for (int idx = tid; idx < total; idx += 256) {
    int il = idx / NW, w = idx - il * NW;
    gout[idx] = tile[il * 49 + w];
  }
}

// ------- NMS: block-64 mask propagation (1 wave/batch) + emit rois ----------
__global__ void nms_k(const unsigned long long* __restrict__ sup,
                      const unsigned long long* __restrict__ vwp,
                      const double* __restrict__ bsort,
                      float* __restrict__ out) {
  int n = blockIdx.x; int l = threadIdx.x;   // 64 threads = 1 wave
  unsigned long long vw = (l < NW) ? vwp[n * NW + l] : 0ULL;
  unsigned long long remv = 0ULL, keepw = 0ULL;
  const unsigned long long* sbase = sup + (size_t)n * NPRE * NW;
  unsigned long long r = (l < NPRE) ? sbase[(size_t)l * NW] : 0ULL;  // b=0 diag
  for (int b = 0; b < NW; ++b) {
    unsigned long long rn = 0ULL;
    if (b + 1 < NW) {
      int gi = (b + 1) * 64 + l;
      if (gi < NPRE) rn = sbase[(size_t)gi * NW + (b + 1)];
    }
    unsigned long long kept = __shfl(vw & ~remv, b);
    unsigned long long todo = kept;
    while (todo) {
      int i = __builtin_ctzll(todo);
      unsigned long long ri = __shfl(r, i);
      kept &= ~ri;
      todo &= todo - 1;
      todo &= ~ri;
    }
    if (l == b) keepw = kept;
    unsigned long long m = kept;
    while (m) {
      int i0 = __builtin_ctzll(m); m &= m - 1;
      int i1 = -1, i2 = -1, i3 = -1, i4 = -1, i5 = -1, i6 = -1, i7 = -1;
      if (m) { i1 = __builtin_ctzll(m); m &= m - 1; }
      if (m) { i2 = __builtin_ctzll(m); m &= m - 1; }
      if (m) { i3 = __builtin_ctzll(m); m &= m - 1; }
      if (m) { i4 = __builtin_ctzll(m); m &= m - 1; }
      if (m) { i5 = __builtin_ctzll(m); m &= m - 1; }
      if (m) { i6 = __builtin_ctzll(m); m &= m - 1; }
      if (m) { i7 = __builtin_ctzll(m); m &= m - 1; }
      if (l < NW) {
        const unsigned long long* rb = sbase + (size_t)(b << 6) * NW + l;
        unsigned long long a0 = rb[(size_t)i0 * NW];
        unsigned long long a1 = (i1 >= 0) ? rb[(size_t)i1 * NW] : 0ULL;
        unsigned long long a2 = (i2 >= 0) ? rb[(size_t)i2 * NW] : 0ULL;
        unsigned long long a3 = (i3 >= 0) ? rb[(size_t)i3 * NW] : 0ULL;
        unsigned long long a4 = (i4 >= 0) ? rb[(size_t)i4 * NW] : 0ULL;
        unsigned long long a5 = (i5 >= 0) ? rb[(size_t)i5 * NW] : 0ULL;
        unsigned long long a6 = (i6 >= 0) ? rb[(size_t)i6 * NW] : 0ULL;
        unsigned long long a7 = (i7 >= 0) ? rb[(size_t)i7 * NW] : 0ULL;
        remv |= (((a0 | a1) | (a2 | a3)) | ((a4 | a5) | (a6 | a7)));
      }
    }
    r = rn;
  }
  unsigned long long keep = keepw;
  int cnt = __popcll(keep);
  int pre = cnt;
#pragma unroll
  for (int d = 1; d < 64; d <<= 1) {
    int tt = __shfl_up(pre, d);
    if (l >= d) pre += tt;
  }
  int nk = __shfl(pre, 63);
  int excl = pre - cnt;
  __shared__ float sbox[NPOST * 4];
  unsigned long long m2 = keep; int rank = excl;
  while (m2) {
    int b = __builtin_ctzll(m2);
    m2 &= m2 - 1;
    if (rank < NPOST) {
      int j = (l << 6) + b;
      const double* bj = bsort + ((size_t)n * NPRE + j) * 4;
      sbox[rank*4]   = (float)bj[0]; sbox[rank*4+1] = (float)bj[1];
      sbox[rank*4+2] = (float)bj[2]; sbox[rank*4+3] = (float)bj[3];
    }
    ++rank;
  }
  __syncthreads();
  if (nk == 0 && l == 0) {
    const double* b0 = bsort + (size_t)n * NPRE * 4;
    sbox[0] = (float)b0[0]; sbox[1] = (float)b0[1];
    sbox[2] = (float)b0[2]; sbox[3] = (float)b0[3];
  }
  __syncthreads();
  int nke = nk > 0 ? nk : 1;
  for (int r2 = l; r2 < NPOST; r2 += 64) {
    int src = r2 < nke ? r2 : r2 % nke;
    float4 b4 = *(float4*)(sbox + src * 4);
    *(float4*)(out + OFF_ROIS + ((size_t)n * NPOST + r2) * 4) = b4;
    out[OFF_IDX + n * NPOST + r2] = (float)n;
  }
}

extern "C" void kernel_launch(void* const* d_in, const int* in_sizes, int n_in,
                              void* d_out, int out_size, void* d_ws, size_t ws_size,
                              hipStream_t stream) {
  const float* X  = (const float*)d_in[0];
  const float* CW = (const float*)d_in[1];
  const float* CB = (const float*)d_in[2];
  const float* SW = (const float*)d_in[3];
  const float* SB = (const float*)d_in[4];
  const float* LW = (const float*)d_in[5];
  const float* LB = (const float*)d_in[6];
  const int*   IH = (const int*)d_in[7];
  const int*   IW = (const int*)d_in[8];
  float* out = (float*)d_out;
  char* ws = (char*)d_ws;

  // ws carve. sup OVERLAYS feat (feat dead after heads_k). Peak: 14,949,504 B.
  float* feat = (float*)(ws + 0);                                  // 11,829,248
  unsigned long long* sup  = (unsigned long long*)(ws + 0);        //  4,512,000 (overlay)
  float* Wt    = (float*)(ws + 11829248);                          //    131,072
  double* boxes= (double*)(ws + 12376192);                         //  1,663,488
  unsigned long long* keys = (unsigned long long*)(ws + 14039680); //    524,288
  double* bsort= (double*)(ws + 14563968);                         //    384,000
  unsigned long long* vw   = (unsigned long long*)(ws + 14947968); //      1,536

  hipLaunchKernelGGL(wt_k,     dim3(128),      dim3(256),  0, stream, LW, SW, Wt, keys);
  hipLaunchKernelGGL(conv_k,   dim3(38, 8, 4), dim3(256),  0, stream, X, CW, CB, feat);
  hipLaunchKernelGGL(heads_k,  dim3(361, 4),   dim3(256),  0, stream,
                     feat, Wt, LB, SB, IH, IW, out, boxes, keys);
  hipLaunchKernelGGL(sortA1_k, dim3(32),       dim3(1024), 0, stream, keys);
  hipLaunchKernelGGL(sortA2_k, dim3(8),        dim3(1024), 0, stream, keys);
  hipLaunchKernelGGL(sortCG_k, dim3(4),        dim3(1024), 0, stream, keys, boxes, bsort, vw);
  hipLaunchKernelGGL(iou_k,    dim3(47, 4),    dim3(256),  0, stream, bsort, sup);
  hipLaunchKernelGGL(nms_k,    dim3(4),        dim3(64),   0, stream, sup, vw, bsort, out);
}

// Round 13
// 964.745 us; speedup vs baseline: 1.0366x; 1.0366x over previous
//
#include <hip/hip_runtime.h>
#include <cstdint>
#include <cstddef>

#define HW    1444      // 38*38
#define NA    12996     // HW*9
#define NPRE  3000
#define NW    47        // ceil(3000/64)
#define NPOST 300

// d_out section offsets (in floats)
#define OFF_LOCS   0         // 4*12996*4 = 207936
#define OFF_SCORES 207936    // 4*12996*2 = 103968
#define OFF_ROIS   311904    // 1200*4    = 4800
#define OFF_IDX    316704    // 4*300     = 1200
#define OFF_ANCH   317904    // 12996*4   = 51984

#define INVALID_KEY 0xFFF0000000000000ULL

typedef float f32x2 __attribute__((ext_vector_type(2)));
typedef float f32x4 __attribute__((ext_vector_type(4)));

__device__ inline double as_dim(int raw) {
  if (raw > 0 && raw < 1000000) return (double)raw;
  return (double)__int_as_float(raw);
}

// ------- 3x3 conv: R9 VERBATIM (best measured: 564-573us, 0 conflicts) -----
__global__ __launch_bounds__(256) void conv_k(const float* __restrict__ X,
                                              const float* __restrict__ W,
                                              const float* __restrict__ B,
                                              float* __restrict__ F) {
  __shared__ float Xs[1008];   // A: [4cl][3row][40]=480 | B: [4cl][3row][44]=528
  __shared__ float Wsf[2304];  // [o=64][36] f32, 9216 B, lane-contiguous
  const int tid  = threadIdx.x;
  const int lane = tid & 63;
  const int wv   = tid >> 6;
  const int seg  = wv * 10;
  const int y  = blockIdx.x;
  const int o0 = blockIdx.y * 64;
  const int n  = blockIdx.z;
  const float* xn = X + ((size_t)n * 512) * HW;

  int xsrcA[2]; bool xvalA[2]; bool xactA1;
  {
    int e = tid;
    int cl = e / 120, rem = e - cl * 120, row = rem / 40, colA = rem - row * 40;
    int m = colA - 1, iy = y - 1 + row;
    xvalA[0] = (m >= 0 && m < 38 && iy >= 0 && iy < 38);
    xsrcA[0] = xvalA[0] ? (cl * HW + iy * 38 + m) : 0;
  }
  {
    int e = tid + 256; xactA1 = (e < 480);
    int cl = e / 120, rem = e - cl * 120, row = rem / 40, colA = rem - row * 40;
    int m = colA - 1, iy = y - 1 + row;
    xvalA[1] = xactA1 && (m >= 0 && m < 38 && iy >= 0 && iy < 38);
    xsrcA[1] = xvalA[1] ? (cl * HW + iy * 38 + m) : 0;
  }
  int xsrcB[3]; bool xvalB[3]; bool xactB2;
#pragma unroll
  for (int u = 0; u < 3; ++u) {
    int e = tid + u * 256;
    bool act = (e < 528);
    int cl = e / 132, rem = e - cl * 132, row = rem / 44, colB = rem - row * 44;
    int m = colB - 3, iy = y - 1 + row;
    xvalB[u] = act && (m >= 0 && m < 38 && iy >= 0 && iy < 38);
    xsrcB[u] = xvalB[u] ? (cl * HW + iy * 38 + m) : 0;
    if (u == 2) xactB2 = act;
  }
  int wsrc[9];
#pragma unroll
  for (int u = 0; u < 9; ++u) {
    int e = tid + u * 256;
    int ol = e / 36, t36 = e - ol * 36;
    wsrc[u] = (o0 + ol) * 4608 + t36;
  }

  float xrA[2], xrB[3], wr_[9];
#pragma unroll
  for (int u = 0; u < 2; ++u) xrA[u] = xvalA[u] ? xn[xsrcA[u]] : 0.f;
#pragma unroll
  for (int u = 0; u < 3; ++u) xrB[u] = xvalB[u] ? xn[xsrcB[u]] : 0.f;
#pragma unroll
  for (int u = 0; u < 9; ++u) wr_[u] = W[wsrc[u]];

  double acc[10];
#pragma unroll
  for (int p = 0; p < 10; ++p) acc[p] = 0.;
  f32x2 pA[5], pB[5];
  float pc0 = 0.f;

  const int  xb0   = (wv & 1) ? (480 + seg + 2) : seg;
  const int  cstep = (wv & 1) ? 132 : 120;
  const int  kstep = (wv & 1) ? 44 : 40;

#define WQ_ELEM(t) ((t & 3) == 0 ? wq[(t) >> 2].x : (t & 3) == 1 ? wq[(t) >> 2].y : \
                    (t & 3) == 2 ? wq[(t) >> 2].z : wq[(t) >> 2].w)

  for (int cc = 0; cc < 128; ++cc) {
    __syncthreads();
    Xs[tid] = xrA[0];
    if (xactA1) Xs[tid + 256] = xrA[1];
    Xs[480 + tid] = xrB[0];
    Xs[480 + tid + 256] = xrB[1];
    if (xactB2) Xs[480 + tid + 512] = xrB[2];
#pragma unroll
    for (int u = 0; u < 9; ++u) Wsf[tid + u * 256] = wr_[u];
    __syncthreads();
    if (cc < 127) {
      const int cb = (cc + 1) * 4;
#pragma unroll
      for (int u = 0; u < 2; ++u) xrA[u] = xvalA[u] ? xn[cb * HW + xsrcA[u]] : 0.f;
#pragma unroll
      for (int u = 0; u < 3; ++u) xrB[u] = xvalB[u] ? xn[cb * HW + xsrcB[u]] : 0.f;
#pragma unroll
      for (int u = 0; u < 9; ++u) wr_[u] = W[wsrc[u] + (cc + 1) * 36];
    }
    f32x4 wq[9];
    {
      const f32x4* wrow = (const f32x4*)&Wsf[lane * 36];
#pragma unroll
      for (int q = 0; q < 9; ++q) wq[q] = wrow[q];
    }
    if ((cc & 1) == 0) {
#pragma unroll
      for (int a = 0; a < 5; ++a) { pA[a] = (f32x2)(0.f); pB[a] = (f32x2)(0.f); }
      pc0 = 0.f;
    }
#pragma unroll
    for (int cl = 0; cl < 4; ++cl) {
      f32x2 wp[9];
#pragma unroll
      for (int k = 0; k < 9; ++k) {
        float wv0 = WQ_ELEM(cl * 9 + k);
        wp[k][0] = wv0; wp[k][1] = wv0;
      }
#pragma unroll
      for (int ky = 0; ky < 3; ++ky) {
        const float* xrow = &Xs[xb0 + cl * cstep + ky * kstep]; // 16B-aligned
        f32x4 q0 = *(const f32x4*)(xrow);
        f32x4 q1 = *(const f32x4*)(xrow + 4);
        f32x4 q2 = *(const f32x4*)(xrow + 8);
        f32x2 xp[6];
        xp[0] = __builtin_shufflevector(q0, q0, 0, 1);
        xp[1] = __builtin_shufflevector(q0, q0, 2, 3);
        xp[2] = __builtin_shufflevector(q1, q1, 0, 1);
        xp[3] = __builtin_shufflevector(q1, q1, 2, 3);
        xp[4] = __builtin_shufflevector(q2, q2, 0, 1);
        xp[5] = __builtin_shufflevector(q2, q2, 2, 3);
#pragma unroll
        for (int a = 0; a < 5; ++a)
          asm("v_pk_fma_f32 %0, %1, %2, %0"
              : "+v"(pA[a]) : "v"(xp[a]), "v"(wp[ky * 3 + 0]));
        pc0 = fmaf(wp[ky * 3 + 1][0], xp[0][1], pc0);
#pragma unroll
        for (int a = 0; a < 5; ++a)
          asm("v_pk_fma_f32 %0, %1, %2, %0"
              : "+v"(pB[a]) : "v"(xp[a + 1]), "v"(wp[ky * 3 + 1]));
#pragma unroll
        for (int a = 0; a < 5; ++a)
          asm("v_pk_fma_f32 %0, %1, %2, %0"
              : "+v"(pA[a]) : "v"(xp[a + 1]), "v"(wp[ky * 3 + 2]));
      }
    }
    if (cc & 1) {
      acc[0] += (double)(pA[0][0] + pc0);
#pragma unroll
      for (int p = 1; p < 10; ++p) {
        float sa = pA[p >> 1][p & 1];
        float sb = (p & 1) ? pB[(p - 1) >> 1][0] : pB[(p - 2) >> 1][1];
        acc[p] += (double)(sa + sb);
      }
    }
  }
  double bb = (double)B[o0 + lane];
  float* fp = F + ((size_t)(n * 512 + o0 + lane)) * HW + y * 38;
#pragma unroll
  for (int p = 0; p < 10; ++p) {
    int col = seg + p;
    if (col < 38) fp[col] = (float)fmax(acc[p] + bb, 0.0);
  }
}

// ------- heads: direct lw/sw float4 reads + fused decode/keys + pad ---------
// R13: Wt[c*64+o] == lw[o*512+c] (contiguous in c) -> read lw/sw directly as
// float4 (128 b128 loads/thread, was 512 scalar Wt loads). FMA order stays
// c-ascending element-by-element -> acc BIT-IDENTICAL. sf staging vectorized
// (same values). wt_k deleted; its keys-padding folded into surplus threads.
__global__ __launch_bounds__(256) void heads_k(const float* __restrict__ F,
                                               const float* __restrict__ lw,
                                               const float* __restrict__ sw,
                                               const float* __restrict__ lb,
                                               const float* __restrict__ sb,
                                               const int* __restrict__ ihp,
                                               const int* __restrict__ iwp,
                                               float* __restrict__ out,
                                               double* __restrict__ boxes,
                                               unsigned long long* __restrict__ keys) {
  __shared__ float sf[512 * 4];
  __shared__ double ssc[4][18];
  __shared__ float sloc[4][36];
  int n = blockIdx.y;
  int p0 = blockIdx.x * 4;
  int tid = threadIdx.x;
  // pad keys for i in [NA,16384) (was wt_k's job); completes before sortA
  int gid = (blockIdx.y * 361 + blockIdx.x) * 256 + tid;
  if (gid < 4 * (16384 - NA)) {
    int n2 = gid / (16384 - NA), r = gid - n2 * (16384 - NA);
    keys[((size_t)n2 << 14) + NA + r] = ~0ULL;
  }
  const float* fn = F + ((size_t)n * 512) * HW;
  for (int c = tid; c < 512; c += 256) {
    f32x4 v = *(const f32x4*)(fn + (size_t)c * HW + p0);   // 16B-aligned
    *(f32x4*)(sf + (c << 2)) = v;
  }
  __syncthreads();
  int pl = tid & 3, o = tid >> 2;
  double acc = 0.;
  if (o < 54) {
    const float* wrow = (o < 36) ? (lw + (size_t)o * 512) : (sw + (size_t)(o - 36) * 512);
    for (int c = 0; c < 512; c += 4) {
      f32x4 w4 = *(const f32x4*)(wrow + c);                // 16B-aligned
      acc = fma((double)w4.x, (double)sf[((c + 0) << 2) | pl], acc);
      acc = fma((double)w4.y, (double)sf[((c + 1) << 2) | pl], acc);
      acc = fma((double)w4.z, (double)sf[((c + 2) << 2) | pl], acc);
      acc = fma((double)w4.w, (double)sf[((c + 3) << 2) | pl], acc);
    }
  }
  int p = p0 + pl;
  if (o < 36) {
    acc += (double)lb[o];
    float v = (float)acc;
    out[OFF_LOCS + ((size_t)n * NA + (size_t)p * 9 + (o >> 2)) * 4 + (o & 3)] = v;
    sloc[pl][o] = v;
  } else if (o < 54) {
    int oo = o - 36;
    acc += (double)sb[oo];
    out[OFF_SCORES + ((size_t)n * NA + (size_t)p * 9 + (oo >> 1)) * 2 + (oo & 1)] = (float)acc;
    ssc[pl][oo] = acc;
  }
  __syncthreads();
  if (tid < 36) {
    int pl2 = tid / 9, a = tid - pl2 * 9;
    double s0 = ssc[pl2][a * 2], s1 = ssc[pl2][a * 2 + 1];
    double mx = fmax(s0, s1);
    double e0 = exp(s0 - mx), e1 = exp(s1 - mx);
    double sc = e1 / (e0 + e1);
    int pp = p0 + pl2;
    int i = pp * 9 + a;
    int ri = a / 3, si = a - ri * 3;
    double sr  = (ri == 0) ? 0.7071067811865476 : (ri == 1 ? 1.0 : 1.4142135623730951);
    double sri = (ri == 0) ? 1.4142135623730951 : (ri == 1 ? 1.0 : 0.7071067811865476);
    double hs = (double)(128 << si) * sr;
    double wd = (double)(128 << si) * sri;
    int py = pp / 38, px = pp - py * 38;
    float sx = (float)(px * 16), sy = (float)(py * 16);
    float fx1 = (float)(8.0 - 0.5 * wd), fy1 = (float)(8.0 - 0.5 * hs);
    float fx2 = (float)(8.0 + 0.5 * wd), fy2 = (float)(8.0 + 0.5 * hs);
    float ax1f = sx + fx1, ay1f = sy + fy1, ax2f = sx + fx2, ay2f = sy + fy2;
    if (n == 0) {
      float* ap = out + OFF_ANCH + (size_t)i * 4;
      ap[0] = ax1f; ap[1] = ay1f; ap[2] = ax2f; ap[3] = ay2f;
    }
    double ax1 = ax1f, ay1 = ay1f, ax2 = ax2f, ay2 = ay2f;
    double aw = ax2 - ax1, ah = ay2 - ay1;
    double acx = ax1 + 0.5 * aw, acy = ay1 + 0.5 * ah;
    double l0 = (double)sloc[pl2][a * 4 + 0], l1 = (double)sloc[pl2][a * 4 + 1];
    double l2 = (double)sloc[pl2][a * 4 + 2], l3 = (double)sloc[pl2][a * 4 + 3];
    double cx = l0 * aw + acx, cy = l1 * ah + acy;
    double bw = aw * exp(l2), bh = ah * exp(l3);
    double iwf = as_dim(iwp[0]), ihf = as_dim(ihp[0]);
    double x1 = fmin(fmax(cx - 0.5 * bw, 0.0), iwf);
    double y1 = fmin(fmax(cy - 0.5 * bh, 0.0), ihf);
    double x2 = fmin(fmax(cx + 0.5 * bw, 0.0), iwf);
    double y2 = fmin(fmax(cy + 0.5 * bh, 0.0), ihf);
    bool valid = ((x2 - x1) >= 16.0) && ((y2 - y1) >= 16.0);
    double* bp = boxes + ((size_t)n * NA + i) * 4;
    bp[0] = x1; bp[1] = y1; bp[2] = x2; bp[3] = y2;
    unsigned long long u = (unsigned long long)__double_as_longlong(sc);
    u = (u >> 63) ? ~u : (u | 0x8000000000000000ULL);
    unsigned long long inv = ~u;
    if (!valid) inv = INVALID_KEY;
    keys[((size_t)n << 14) + i] = (inv & ~0x3FFFULL) | (unsigned long long)i;
  }
}

// ---- sort phase A: per-8192-half in-LDS bitonic sort (R11 measured-best) ---
__global__ __launch_bounds__(1024) void sortA_k(unsigned long long* __restrict__ keys) {
  __shared__ unsigned long long s[8192];   // 64 KB
  const int half = blockIdx.x & 1;
  unsigned long long* g = keys + (((size_t)(blockIdx.x >> 1)) << 14) + ((size_t)half << 13);
  const int tid = threadIdx.x;
  for (int i = tid; i < 8192; i += 1024) s[i] = g[i];
  for (int size = 2; size <= 8192; size <<= 1) {
    for (int stride = size >> 1; stride > 0; stride >>= 1) {
      __syncthreads();
      for (int u = tid; u < 4096; u += 1024) {
        int lo = u & (stride - 1);
        int i1 = ((u - lo) << 1) | lo;
        int i2 = i1 + stride;
        bool up = (i1 & size) == 0;
        if (half) up = !up;   // upper half sorts descending
        unsigned long long a = s[i1], b = s[i2];
        if ((a > b) == up) { s[i1] = b; s[i2] = a; }
      }
    }
  }
  __syncthreads();
  for (int i = tid; i < 8192; i += 1024) g[i] = s[i];
}

// ---- sort final merge + gather, FUSED (R11 verbatim) -----------------------
__global__ __launch_bounds__(1024) void sortCG_k(const unsigned long long* __restrict__ keys,
                                                 const double* __restrict__ boxes,
                                                 double* __restrict__ bsort,
                                                 unsigned long long* __restrict__ vw) {
  __shared__ unsigned long long s[8192];
  const int n = blockIdx.x;
  const unsigned long long* g = keys + ((size_t)n << 14);
  const int tid = threadIdx.x;
  for (int i = tid; i < 8192; i += 1024) {
    unsigned long long a = g[i], b = g[i + 8192];
    s[i] = a < b ? a : b;
  }
  for (int stride = 4096; stride > 0; stride >>= 1) {
    __syncthreads();
    for (int u = tid; u < 4096; u += 1024) {
      int lo = u & (stride - 1);
      int i1 = ((u - lo) << 1) | lo;
      int i2 = i1 + stride;
      unsigned long long a = s[i1], b = s[i2];
      if (a > b) { s[i1] = b; s[i2] = a; }
    }
  }
  __syncthreads();
  const int lane = tid & 63;
#pragma unroll
  for (int r3 = 0; r3 < 3; ++r3) {
    int r = r3 * 1024 + tid;
    bool valid = false;
    if (r < NPRE) {
      unsigned long long kk = s[r];
      valid = kk < INVALID_KEY;
      unsigned idx = (unsigned)(kk & 0x3FFFULL);
      const double* bp = boxes + ((size_t)n * NA + idx) * 4;
      double* dp = bsort + ((size_t)n * NPRE + r) * 4;
      dp[0] = bp[0]; dp[1] = bp[1]; dp[2] = bp[2]; dp[3] = bp[3];
    }
    unsigned long long mask = __ballot(valid);
    int w = r >> 6;
    if (lane == 0 && w < NW) vw[n * NW + w] = mask;
  }
}

// ------- suppression matrix (R11 measured-best form, mul-threshold) ---------
__global__ __launch_bounds__(256) void iou_k(const double* __restrict__ bsort,
                                             unsigned long long* __restrict__ sup) {
  int t = blockIdx.x * 256 + threadIdx.x;
  if (t >= 4 * NPRE * NW) return;
  int w = t % NW; int rest = t / NW; int i = rest % NPRE; int n = rest / NPRE;
  const double* bb = bsort + (size_t)n * NPRE * 4;
  double bix1 = bb[(size_t)i*4], biy1 = bb[(size_t)i*4+1];
  double bix2 = bb[(size_t)i*4+2], biy2 = bb[(size_t)i*4+3];
  double ai = (bix2 - bix1) * (biy2 - biy1);
  unsigned long long word = 0ULL;
  int j0 = w << 6;
  if (j0 + 63 > i) {
    int lmax = NPRE - j0; if (lmax > 64) lmax = 64;
    for (int l = 0; l < lmax; ++l) {
      int j = j0 + l;
      if (j <= i) continue;
      const double* bj = bb + (size_t)j * 4;
      double aj = (bj[2] - bj[0]) * (bj[3] - bj[1]);
      double xx1 = fmax(bix1, bj[0]), yy1 = fmax(biy1, bj[1]);
      double xx2 = fmin(bix2, bj[2]), yy2 = fmin(biy2, bj[3]);
      double inter = fmax(xx2 - xx1, 0.0) * fmax(yy2 - yy1, 0.0);
      double uni = ai + aj - inter;
      bool supb = (uni > 0.0) && (inter > 0.7 * uni);
      word |= (unsigned long long)supb << l;
    }
  }
  sup[((size_t)n * NPRE + i) * NW + w] = word;
}

// ------- NMS: block-64 mask propagation (1 wave/batch) + emit rois ----------
__global__ void nms_k(const unsigned long long* __restrict__ sup,
                      const unsigned long long* __restrict__ vwp,
                      const double* __restrict__ bsort,
                      float* __restrict__ out) {
  int n = blockIdx.x; int l = threadIdx.x;   // 64 threads = 1 wave
  unsigned long long vw = (l < NW) ? vwp[n * NW + l] : 0ULL;
  unsigned long long remv = 0ULL, keepw = 0ULL;
  const unsigned long long* sbase = sup + (size_t)n * NPRE * NW;
  unsigned long long r = (l < NPRE) ? sbase[(size_t)l * NW] : 0ULL;  // b=0 diag
  for (int b = 0; b < NW; ++b) {
    unsigned long long rn = 0ULL;
    if (b + 1 < NW) {
      int gi = (b + 1) * 64 + l;
      if (gi < NPRE) rn = sbase[(size_t)gi * NW + (b + 1)];
    }
    unsigned long long kept = __shfl(vw & ~remv, b);
    unsigned long long todo = kept;
    while (todo) {
      int i = __builtin_ctzll(todo);
      unsigned long long ri = __shfl(r, i);
      kept &= ~ri;
      todo &= todo - 1;
      todo &= ~ri;
    }
    if (l == b) keepw = kept;
    unsigned long long m = kept;
    while (m) {
      int i0 = __builtin_ctzll(m); m &= m - 1;
      int i1 = -1, i2 = -1, i3 = -1, i4 = -1, i5 = -1, i6 = -1, i7 = -1;
      if (m) { i1 = __builtin_ctzll(m); m &= m - 1; }
      if (m) { i2 = __builtin_ctzll(m); m &= m - 1; }
      if (m) { i3 = __builtin_ctzll(m); m &= m - 1; }
      if (m) { i4 = __builtin_ctzll(m); m &= m - 1; }
      if (m) { i5 = __builtin_ctzll(m); m &= m - 1; }
      if (m) { i6 = __builtin_ctzll(m); m &= m - 1; }
      if (m) { i7 = __builtin_ctzll(m); m &= m - 1; }
      if (l < NW) {
        const unsigned long long* rb = sbase + (size_t)(b << 6) * NW + l;
        unsigned long long a0 = rb[(size_t)i0 * NW];
        unsigned long long a1 = (i1 >= 0) ? rb[(size_t)i1 * NW] : 0ULL;
        unsigned long long a2 = (i2 >= 0) ? rb[(size_t)i2 * NW] : 0ULL;
        unsigned long long a3 = (i3 >= 0) ? rb[(size_t)i3 * NW] : 0ULL;
        unsigned long long a4 = (i4 >= 0) ? rb[(size_t)i4 * NW] : 0ULL;
        unsigned long long a5 = (i5 >= 0) ? rb[(size_t)i5 * NW] : 0ULL;
        unsigned long long a6 = (i6 >= 0) ? rb[(size_t)i6 * NW] : 0ULL;
        unsigned long long a7 = (i7 >= 0) ? rb[(size_t)i7 * NW] : 0ULL;
        remv |= (((a0 | a1) | (a2 | a3)) | ((a4 | a5) | (a6 | a7)));
      }
    }
    r = rn;
  }
  unsigned long long keep = keepw;
  int cnt = __popcll(keep);
  int pre = cnt;
#pragma unroll
  for (int d = 1; d < 64; d <<= 1) {
    int tt = __shfl_up(pre, d);
    if (l >= d) pre += tt;
  }
  int nk = __shfl(pre, 63);
  int excl = pre - cnt;
  __shared__ float sbox[NPOST * 4];
  unsigned long long m2 = keep; int rank = excl;
  while (m2) {
    int b = __builtin_ctzll(m2);
    m2 &= m2 - 1;
    if (rank < NPOST) {
      int j = (l << 6) + b;
      const double* bj = bsort + ((size_t)n * NPRE + j) * 4;
      sbox[rank*4]   = (float)bj[0]; sbox[rank*4+1] = (float)bj[1];
      sbox[rank*4+2] = (float)bj[2]; sbox[rank*4+3] = (float)bj[3];
    }
    ++rank;
  }
  __syncthreads();
  if (nk == 0 && l == 0) {
    const double* b0 = bsort + (size_t)n * NPRE * 4;
    sbox[0] = (float)b0[0]; sbox[1] = (float)b0[1];
    sbox[2] = (float)b0[2]; sbox[3] = (float)b0[3];
  }
  __syncthreads();
  int nke = nk > 0 ? nk : 1;
  for (int r2 = l; r2 < NPOST; r2 += 64) {
    int src = r2 < nke ? r2 : r2 % nke;
    float4 b4 = *(float4*)(sbox + src * 4);
    *(float4*)(out + OFF_ROIS + ((size_t)n * NPOST + r2) * 4) = b4;
    out[OFF_IDX + n * NPOST + r2] = (float)n;
  }
}

extern "C" void kernel_launch(void* const* d_in, const int* in_sizes, int n_in,
                              void* d_out, int out_size, void* d_ws, size_t ws_size,
                              hipStream_t stream) {
  const float* X  = (const float*)d_in[0];
  const float* CW = (const float*)d_in[1];
  const float* CB = (const float*)d_in[2];
  const float* SW = (const float*)d_in[3];
  const float* SB = (const float*)d_in[4];
  const float* LW = (const float*)d_in[5];
  const float* LB = (const float*)d_in[6];
  const int*   IH = (const int*)d_in[7];
  const int*   IW = (const int*)d_in[8];
  float* out = (float*)d_out;
  char* ws = (char*)d_ws;

  // ws carve. sup OVERLAYS feat (feat dead after heads_k). Peak: 14,949,504 B.
  float* feat = (float*)(ws + 0);                                  // 11,829,248
  unsigned long long* sup  = (unsigned long long*)(ws + 0);        //  4,512,000 (overlay)
  double* boxes= (double*)(ws + 12376192);                         //  1,663,488
  unsigned long long* keys = (unsigned long long*)(ws + 14039680); //    524,288
  double* bsort= (double*)(ws + 14563968);                         //    384,000
  unsigned long long* vw   = (unsigned long long*)(ws + 14947968); //      1,536

  hipLaunchKernelGGL(conv_k,   dim3(38, 8, 4), dim3(256),  0, stream, X, CW, CB, feat);
  hipLaunchKernelGGL(heads_k,  dim3(361, 4),   dim3(256),  0, stream,
                     feat, LW, SW, LB, SB, IH, IW, out, boxes, keys);
  hipLaunchKernelGGL(sortA_k,  dim3(8),        dim3(1024), 0, stream, keys);
  hipLaunchKernelGGL(sortCG_k, dim3(4),        dim3(1024), 0, stream, keys, boxes, bsort, vw);
  hipLaunchKernelGGL(iou_k,    dim3((4*NPRE*NW + 255) / 256), dim3(256), 0, stream, bsort, sup);
  hipLaunchKernelGGL(nms_k,    dim3(4),        dim3(64),   0, stream, sup, vw, bsort, out);
}